// Round 1
// baseline (305.689 us; speedup 1.0000x reference)
//
#include <hip/hip_runtime.h>
#include <cstdint>

#define S_REAL 1992
#define S_PAD  2048
#define DIMSZ  2048
#define NHEAD  16
#define DHD    128

typedef float f32x4 __attribute__((ext_vector_type(4)));
typedef __bf16 bf16x8 __attribute__((ext_vector_type(8)));
typedef unsigned short u16x8 __attribute__((ext_vector_type(8)));

__device__ __forceinline__ unsigned short f2bf(float f){
  uint32_t u = __float_as_uint(f);
  u += 0x7fffu + ((u >> 16) & 1u);
  return (unsigned short)(u >> 16);
}

__device__ __forceinline__ void gload16(const void* g, void* l){
  __builtin_amdgcn_global_load_lds(
      (const __attribute__((address_space(1))) uint32_t*)g,
      (__attribute__((address_space(3))) uint32_t*)l,
      16, 0, 0);
}

// ---------------- fp32 -> bf16 convert (vectorized) ----------------
__launch_bounds__(256)
__global__ void k_cvt(const float* __restrict__ src, unsigned short* __restrict__ dst, int n8){
  int i = blockIdx.x * 256 + threadIdx.x;
  if (i >= n8) return;
  const float4* s = (const float4*)src + (size_t)i * 2;
  float4 a = s[0], b = s[1];
  u16x8 o;
  o[0]=f2bf(a.x); o[1]=f2bf(a.y); o[2]=f2bf(a.z); o[3]=f2bf(a.w);
  o[4]=f2bf(b.x); o[5]=f2bf(b.y); o[6]=f2bf(b.z); o[7]=f2bf(b.w);
  *((u16x8*)dst + i) = o;
}

// ---------------- GEMM: C[m][n] = sum_k A[m][k]*W[n][k] + bias[n] ----------------
// A bf16 [M][2048] (rows clamped to Mreal-1), W bf16 [2048][2048], C fp32.
// blockIdx.z selects among 3 (for fused QKV); 128x128 tile, BK=64, 4 waves.
__launch_bounds__(256)
__global__ void k_gemm(const unsigned short* __restrict__ A,
                       const unsigned short* __restrict__ B0,
                       const unsigned short* __restrict__ B1,
                       const unsigned short* __restrict__ B2,
                       const float* __restrict__ bias0,
                       const float* __restrict__ bias1,
                       const float* __restrict__ bias2,
                       float* __restrict__ C0, float* __restrict__ C1, float* __restrict__ C2,
                       int Mreal)
{
  __shared__ unsigned short As[128 * 64];
  __shared__ unsigned short Bs[128 * 64];
  const unsigned short* B = (blockIdx.z == 0) ? B0 : ((blockIdx.z == 1) ? B1 : B2);
  const float* bias        = (blockIdx.z == 0) ? bias0 : ((blockIdx.z == 1) ? bias1 : bias2);
  float* C                 = (blockIdx.z == 0) ? C0 : ((blockIdx.z == 1) ? C1 : C2);

  const int t = threadIdx.x;
  const int w = t >> 6, l = t & 63;
  const int lr = l & 15, lg = l >> 4;
  const int m0 = blockIdx.x * 128, n0 = blockIdx.y * 128;
  const int wr = (w >> 1) * 64, wc = (w & 1) * 64;
  const int srow = l >> 3;          // row within 8-row staging chunk
  const int scol = (l & 7) * 8;     // k offset within 64

  f32x4 acc[4][4];
  #pragma unroll
  for (int mi = 0; mi < 4; ++mi)
    #pragma unroll
    for (int ni = 0; ni < 4; ++ni)
      acc[mi][ni] = (f32x4){0.f, 0.f, 0.f, 0.f};

  for (int kt = 0; kt < DIMSZ / 64; ++kt){
    __syncthreads();
    const int k0 = kt * 64;
    #pragma unroll
    for (int i = 0; i < 4; ++i){
      int rl = (w * 4 + i) * 8 + srow;
      int gr = m0 + rl; if (gr > Mreal - 1) gr = Mreal - 1;
      gload16(A + (size_t)gr * DIMSZ + k0 + scol, &As[(w * 4 + i) * 512]);
      gload16(B + (size_t)(n0 + rl) * DIMSZ + k0 + scol, &Bs[(w * 4 + i) * 512]);
    }
    __syncthreads();

    bf16x8 af[4][2], bfr[4][2];
    #pragma unroll
    for (int mi = 0; mi < 4; ++mi)
      #pragma unroll
      for (int ks = 0; ks < 2; ++ks)
        af[mi][ks] = *(const bf16x8*)&As[(wr + mi * 16 + lr) * 64 + ks * 32 + lg * 8];
    #pragma unroll
    for (int ni = 0; ni < 4; ++ni)
      #pragma unroll
      for (int ks = 0; ks < 2; ++ks)
        bfr[ni][ks] = *(const bf16x8*)&Bs[(wc + ni * 16 + lr) * 64 + ks * 32 + lg * 8];
    #pragma unroll
    for (int mi = 0; mi < 4; ++mi)
      #pragma unroll
      for (int ni = 0; ni < 4; ++ni)
        #pragma unroll
        for (int ks = 0; ks < 2; ++ks)
          acc[mi][ni] = __builtin_amdgcn_mfma_f32_16x16x32_bf16(af[mi][ks], bfr[ni][ks], acc[mi][ni], 0, 0, 0);
  }

  #pragma unroll
  for (int ni = 0; ni < 4; ++ni){
    int col = n0 + wc + ni * 16 + lr;
    float bz = bias[col];
    #pragma unroll
    for (int mi = 0; mi < 4; ++mi){
      #pragma unroll
      for (int j = 0; j < 4; ++j){
        int row = m0 + wr + mi * 16 + lg * 4 + j;
        if (row < Mreal) C[(size_t)row * DIMSZ + col] = acc[mi][ni][j] + bz;
      }
    }
  }
}

// ---------------- RMSNorm + RoPE -> bf16 head layout [h][s_pad][128] ----------------
// swz=1: pre-apply XOR-swizzle on 16B d-blocks (for K, consumed via global_load_lds).
__launch_bounds__(256)
__global__ void k_normrope(const float* __restrict__ Xf, const float* __restrict__ nw,
                           const float* __restrict__ fc, const float* __restrict__ fs,
                           unsigned short* __restrict__ Out, float scale, int swz)
{
  const int s = blockIdx.x;       // 0..2047
  const int t = threadIdx.x;      // 256
  const int w = t >> 6, l = t & 63;
  __shared__ float wred[4];
  float v[8];
  float ss = 0.f;
  if (s < S_REAL){
    const float4* p = (const float4*)(Xf + (size_t)s * DIMSZ) + t * 2;
    float4 a = p[0], b = p[1];
    v[0]=a.x; v[1]=a.y; v[2]=a.z; v[3]=a.w; v[4]=b.x; v[5]=b.y; v[6]=b.z; v[7]=b.w;
    #pragma unroll
    for (int j = 0; j < 8; ++j) ss += v[j] * v[j];
  }
  #pragma unroll
  for (int off = 32; off >= 1; off >>= 1) ss += __shfl_xor(ss, off);
  if (l == 0) wred[w] = ss;
  __syncthreads();
  float tot = wred[0] + wred[1] + wred[2] + wred[3];
  float rinv = rsqrtf(tot * (1.f / DIMSZ) + 1e-6f);

  const int h  = t >> 4;            // head
  const int d0 = (t & 15) * 8;      // within-head dim base
  const int b  = t & 15;            // 16B block index (16 per row)
  const int bsw = swz ? (b ^ (s & 7)) : b;
  unsigned short* dst = Out + ((size_t)h * S_PAD + s) * DHD + bsw * 8;
  u16x8 o;
  if (s < S_REAL){
    #pragma unroll
    for (int i = 0; i < 4; ++i){
      float c_ = fc[s * DHD + d0 + 2 * i];
      float s_ = fs[s * DHD + d0 + 2 * i + 1];
      float x1 = v[2 * i]     * rinv * nw[t * 8 + 2 * i];
      float x2 = v[2 * i + 1] * rinv * nw[t * 8 + 2 * i + 1];
      o[2 * i]     = f2bf((x1 * c_ - x2 * s_) * scale);
      o[2 * i + 1] = f2bf((x1 * s_ + x2 * c_) * scale);
    }
  } else {
    #pragma unroll
    for (int j = 0; j < 8; ++j) o[j] = 0;
  }
  *(u16x8*)dst = o;
}

// ---------------- V transpose: fp32 [s][2048] -> bf16 [c=h*128+d][s_pad], swizzled ----------------
__launch_bounds__(256)
__global__ void k_vtrans(const float* __restrict__ Vf, unsigned short* __restrict__ Vth)
{
  __shared__ unsigned short tile[64][72];
  const int t = threadIdx.x;
  const int s0 = blockIdx.x * 64, c0 = blockIdx.y * 64;
  #pragma unroll
  for (int i = 0; i < 4; ++i){
    int r = (t >> 4) * 4 + i;
    int s = s0 + r;
    int cq = (t & 15) * 4;
    float4 val = {0.f, 0.f, 0.f, 0.f};
    if (s < S_REAL) val = *((const float4*)(Vf + (size_t)s * DIMSZ + c0) + (t & 15));
    tile[r][cq + 0] = f2bf(val.x);
    tile[r][cq + 1] = f2bf(val.y);
    tile[r][cq + 2] = f2bf(val.z);
    tile[r][cq + 3] = f2bf(val.w);
  }
  __syncthreads();
  const int cl = t >> 2;
  const int cc = c0 + cl;
  #pragma unroll
  for (int bi = 0; bi < 2; ++bi){
    int b = (t & 3) * 2 + bi;          // source s-block of 8
    u16x8 o;
    #pragma unroll
    for (int j = 0; j < 8; ++j) o[j] = tile[b * 8 + j][cl];
    int bsw = b ^ (cc & 7);
    *(u16x8*)(Vth + (size_t)cc * S_PAD + s0 + bsw * 8) = o;
  }
}

// ---------------- flash attention: 4 waves x 16 q-rows, KV tiles of 64 ----------------
__launch_bounds__(256)
__global__ void k_attn(const unsigned short* __restrict__ Qh,
                       const unsigned short* __restrict__ Kh,
                       const unsigned short* __restrict__ Vth,
                       unsigned short* __restrict__ O)
{
  __shared__ unsigned short kbuf[64 * 128];   // [kv][d] swizzled, 16KB
  __shared__ unsigned short vbuf[128 * 64];   // [d][kv] swizzled, 16KB
  __shared__ unsigned short pbuf[4][16 * 64]; // per-wave P, swizzled
  const int h = blockIdx.y;
  const int q0 = blockIdx.x * 64;
  const int t = threadIdx.x, w = t >> 6, l = t & 63;
  const int lr = l & 15, lg = l >> 4;

  // Q fragments in registers (A-operand rows = wave's 16 q rows)
  const unsigned short* Qp = Qh + ((size_t)h * S_PAD + q0 + w * 16 + lr) * DHD;
  bf16x8 qf[4];
  #pragma unroll
  for (int ks = 0; ks < 4; ++ks) qf[ks] = *(const bf16x8*)(Qp + ks * 32 + lg * 8);

  f32x4 acc[8];
  #pragma unroll
  for (int nf = 0; nf < 8; ++nf) acc[nf] = (f32x4){0.f, 0.f, 0.f, 0.f};
  float m[4], lsum[4];
  #pragma unroll
  for (int j = 0; j < 4; ++j){ m[j] = -3.0e38f; lsum[j] = 0.f; }

  for (int kt = 0; kt < S_PAD / 64; ++kt){
    __syncthreads();
    #pragma unroll
    for (int i = 0; i < 4; ++i){
      int rK = (w * 4 + i) * 4 + (l >> 4);
      gload16(Kh + ((size_t)h * S_PAD + kt * 64 + rK) * DHD + (l & 15) * 8, &kbuf[(w * 4 + i) * 512]);
      int rV = (w * 4 + i) * 8 + (l >> 3);
      gload16(Vth + ((size_t)h * DHD + rV) * S_PAD + kt * 64 + (l & 7) * 8, &vbuf[(w * 4 + i) * 512]);
    }
    __syncthreads();

    // S = Q K^T (pre-scaled Q)
    f32x4 sf[4];
    #pragma unroll
    for (int kvf = 0; kvf < 4; ++kvf){
      sf[kvf] = (f32x4){0.f, 0.f, 0.f, 0.f};
      int r = kvf * 16 + lr;
      #pragma unroll
      for (int ks = 0; ks < 4; ++ks){
        int blk = (ks * 4 + lg) ^ (r & 7);
        bf16x8 kf = *(const bf16x8*)&kbuf[r * 128 + blk * 8];
        sf[kvf] = __builtin_amdgcn_mfma_f32_16x16x32_bf16(qf[ks], kf, sf[kvf], 0, 0, 0);
      }
    }

    // online softmax (rows = lg*4+j, cols across 16-lane group)
    float rowmax[4], rowsum[4], fr[4];
    #pragma unroll
    for (int j = 0; j < 4; ++j)
      rowmax[j] = fmaxf(fmaxf(sf[0][j], sf[1][j]), fmaxf(sf[2][j], sf[3][j]));
    #pragma unroll
    for (int off = 1; off <= 8; off <<= 1)
      #pragma unroll
      for (int j = 0; j < 4; ++j) rowmax[j] = fmaxf(rowmax[j], __shfl_xor(rowmax[j], off));
    #pragma unroll
    for (int j = 0; j < 4; ++j){
      float mn = fmaxf(m[j], rowmax[j]);
      fr[j] = __expf(m[j] - mn);
      m[j] = mn;
    }
    float p[4][4];
    #pragma unroll
    for (int kvf = 0; kvf < 4; ++kvf)
      #pragma unroll
      for (int j = 0; j < 4; ++j) p[kvf][j] = __expf(sf[kvf][j] - m[j]);
    #pragma unroll
    for (int j = 0; j < 4; ++j) rowsum[j] = p[0][j] + p[1][j] + p[2][j] + p[3][j];
    #pragma unroll
    for (int off = 1; off <= 8; off <<= 1)
      #pragma unroll
      for (int j = 0; j < 4; ++j) rowsum[j] += __shfl_xor(rowsum[j], off);
    f32x4 fv = (f32x4){fr[0], fr[1], fr[2], fr[3]};
    #pragma unroll
    for (int j = 0; j < 4; ++j) lsum[j] = lsum[j] * fr[j] + rowsum[j];
    #pragma unroll
    for (int nf = 0; nf < 8; ++nf) acc[nf] *= fv;

    // stage P (wave-local, swizzled; same-wave DS ordering needs no barrier)
    unsigned short* pb = pbuf[w];
    #pragma unroll
    for (int kvf = 0; kvf < 4; ++kvf)
      #pragma unroll
      for (int j = 0; j < 4; ++j){
        int r = lg * 4 + j;
        int c = kvf * 16 + lr;
        int blk = (c >> 3) ^ (r & 7);
        pb[r * 64 + blk * 8 + (c & 7)] = f2bf(p[kvf][j]);
      }

    // O += P V
    bf16x8 pf[2];
    #pragma unroll
    for (int ks = 0; ks < 2; ++ks){
      int blk = (ks * 4 + lg) ^ (lr & 7);
      pf[ks] = *(const bf16x8*)&pb[lr * 64 + blk * 8];
    }
    #pragma unroll
    for (int nf = 0; nf < 8; ++nf){
      int c = nf * 16 + lr;
      #pragma unroll
      for (int ks = 0; ks < 2; ++ks){
        int blk = (ks * 4 + lg) ^ (c & 7);
        bf16x8 vf = *(const bf16x8*)&vbuf[c * 64 + blk * 8];
        acc[nf] = __builtin_amdgcn_mfma_f32_16x16x32_bf16(pf[ks], vf, acc[nf], 0, 0, 0);
      }
    }
  }

  #pragma unroll
  for (int nf = 0; nf < 8; ++nf){
    #pragma unroll
    for (int j = 0; j < 4; ++j){
      int row = q0 + w * 16 + lg * 4 + j;
      if (row < S_REAL)
        O[(size_t)row * DIMSZ + h * DHD + nf * 16 + lr] = f2bf(acc[nf][j] / lsum[j]);
    }
  }
}

extern "C" void kernel_launch(void* const* d_in, const int* in_sizes, int n_in,
                              void* d_out, int out_size, void* d_ws, size_t ws_size,
                              hipStream_t stream)
{
  const float* hidden = (const float*)d_in[0];
  const float* fc  = (const float*)d_in[1];
  const float* fs  = (const float*)d_in[2];
  const float* wq  = (const float*)d_in[3];
  const float* bq  = (const float*)d_in[4];
  const float* wk  = (const float*)d_in[5];
  const float* bk  = (const float*)d_in[6];
  const float* wv  = (const float*)d_in[7];
  const float* bv  = (const float*)d_in[8];
  const float* nqw = (const float*)d_in[9];
  const float* nkw = (const float*)d_in[10];
  const float* wo  = (const float*)d_in[11];
  const float* bo  = (const float*)d_in[12];
  float* out = (float*)d_out;

  char* ws = (char*)d_ws;
  size_t off = 0;
  auto alloc = [&](size_t bytes) -> void* {
    void* p = ws + off;
    off += (bytes + 255) & ~(size_t)255;
    return p;
  };
  unsigned short* Xb  = (unsigned short*)alloc((size_t)S_REAL * DIMSZ * 2);
  unsigned short* Wqb = (unsigned short*)alloc((size_t)DIMSZ * DIMSZ * 2);
  unsigned short* Wkb = (unsigned short*)alloc((size_t)DIMSZ * DIMSZ * 2);
  unsigned short* Wvb = (unsigned short*)alloc((size_t)DIMSZ * DIMSZ * 2);
  unsigned short* Wob = (unsigned short*)alloc((size_t)DIMSZ * DIMSZ * 2);
  float* Qf = (float*)alloc((size_t)S_REAL * DIMSZ * 4);
  float* Kf = (float*)alloc((size_t)S_REAL * DIMSZ * 4);
  float* Vf = (float*)alloc((size_t)S_REAL * DIMSZ * 4);
  unsigned short* Qhh = (unsigned short*)alloc((size_t)NHEAD * S_PAD * DHD * 2);
  unsigned short* Khh = (unsigned short*)alloc((size_t)NHEAD * S_PAD * DHD * 2);
  unsigned short* Vth = (unsigned short*)alloc((size_t)NHEAD * DHD * S_PAD * 2);
  unsigned short* Oa  = (unsigned short*)alloc((size_t)S_REAL * DIMSZ * 2);

  // convert inputs to bf16
  k_cvt<<<S_REAL * DIMSZ / 8 / 256, 256, 0, stream>>>(hidden, Xb, S_REAL * DIMSZ / 8);
  k_cvt<<<DIMSZ * DIMSZ / 8 / 256, 256, 0, stream>>>(wq, Wqb, DIMSZ * DIMSZ / 8);
  k_cvt<<<DIMSZ * DIMSZ / 8 / 256, 256, 0, stream>>>(wk, Wkb, DIMSZ * DIMSZ / 8);
  k_cvt<<<DIMSZ * DIMSZ / 8 / 256, 256, 0, stream>>>(wv, Wvb, DIMSZ * DIMSZ / 8);
  k_cvt<<<DIMSZ * DIMSZ / 8 / 256, 256, 0, stream>>>(wo, Wob, DIMSZ * DIMSZ / 8);

  // fused QKV projection
  k_gemm<<<dim3(16, 16, 3), 256, 0, stream>>>(Xb, Wqb, Wkb, Wvb, bq, bk, bv, Qf, Kf, Vf, S_REAL);

  // RMSNorm + RoPE -> head layouts (Q carries 1/sqrt(128); K pre-swizzled)
  k_normrope<<<S_PAD, 256, 0, stream>>>(Qf, nqw, fc, fs, Qhh, 0.08838834764831843f, 0);
  k_normrope<<<S_PAD, 256, 0, stream>>>(Kf, nkw, fc, fs, Khh, 1.0f, 1);

  // V -> transposed bf16 [h][d][s_pad], pre-swizzled
  k_vtrans<<<dim3(S_PAD / 64, DIMSZ / 64), 256, 0, stream>>>(Vf, Vth);

  // attention (includes zero-padded KV rows -> exact padded-softmax semantics)
  k_attn<<<dim3(S_PAD / 64, NHEAD), 256, 0, stream>>>(Qhh, Khh, Vth, Oa);

  // output projection
  k_gemm<<<dim3(16, 16, 1), 256, 0, stream>>>(Oa, Wob, Wob, Wob, bo, bo, bo, out, out, out, S_REAL);
}

// Round 2
// 256.050 us; speedup vs baseline: 1.1939x; 1.1939x over previous
//
#include <hip/hip_runtime.h>
#include <cstdint>

#define S_REAL 1992
#define S_PAD  2048
#define DIMSZ  2048
#define NHEAD  16
#define DHD    128

typedef float f32x4 __attribute__((ext_vector_type(4)));
typedef __bf16 bf16x8 __attribute__((ext_vector_type(8)));
typedef unsigned short u16x8 __attribute__((ext_vector_type(8)));

__device__ __forceinline__ unsigned short f2bf(float f){
  uint32_t u = __float_as_uint(f);
  u += 0x7fffu + ((u >> 16) & 1u);
  return (unsigned short)(u >> 16);
}

__device__ __forceinline__ void gload16(const void* g, void* l){
  __builtin_amdgcn_global_load_lds(
      (const __attribute__((address_space(1))) uint32_t*)g,
      (__attribute__((address_space(3))) uint32_t*)l,
      16, 0, 0);
}

template<int N> __device__ __forceinline__ void waitbar(){
  if constexpr (N == 8)      asm volatile("s_waitcnt vmcnt(8)\n\ts_barrier" ::: "memory");
  else if constexpr (N == 6) asm volatile("s_waitcnt vmcnt(6)\n\ts_barrier" ::: "memory");
  else if constexpr (N == 4) asm volatile("s_waitcnt vmcnt(4)\n\ts_barrier" ::: "memory");
  else if constexpr (N == 3) asm volatile("s_waitcnt vmcnt(3)\n\ts_barrier" ::: "memory");
  else                       asm volatile("s_waitcnt vmcnt(0)\n\ts_barrier" ::: "memory");
}

// ---------------- fp32 -> bf16 convert (vectorized) ----------------
__launch_bounds__(256)
__global__ void k_cvt(const float* __restrict__ src, unsigned short* __restrict__ dst, int n8){
  int i = blockIdx.x * 256 + threadIdx.x;
  if (i >= n8) return;
  const float4* s = (const float4*)src + (size_t)i * 2;
  float4 a = s[0], b = s[1];
  u16x8 o;
  o[0]=f2bf(a.x); o[1]=f2bf(a.y); o[2]=f2bf(a.z); o[3]=f2bf(a.w);
  o[4]=f2bf(b.x); o[5]=f2bf(b.y); o[6]=f2bf(b.z); o[7]=f2bf(b.w);
  *((u16x8*)dst + i) = o;
}

// ---------------- deep-pipelined GEMM: C[m][n] = sum_k A[m][k]*W[n][k] + bias[n] ----
// 256 x BN tile, 8 waves (512 thr), BK=32, 4 LDS buffers, loads 3 tiles in flight.
// LDS frag reads XOR-swizzled (blk ^= (row>>1)&3); inverse swizzle pre-applied on the
// per-lane GLOBAL source so global_load_lds dest stays linear (both-sides rule).
// Race-safety: loads for tile t+3 are issued only after the barrier at tile t; the
// barrier guarantees all waves completed their ds_reads of tile t-1 (the previous
// occupant of buffer (t+3)&3), so no in-flight load lands on a buffer in use.
template<int BN>
__launch_bounds__(512, 2)
__global__ void k_gemm8(const unsigned short* __restrict__ A,
                        const unsigned short* __restrict__ B0,
                        const unsigned short* __restrict__ B1,
                        const unsigned short* __restrict__ B2,
                        const float* __restrict__ bias0,
                        const float* __restrict__ bias1,
                        const float* __restrict__ bias2,
                        float* __restrict__ C0, float* __restrict__ C1, float* __restrict__ C2,
                        int Mreal)
{
  constexpr int WN   = BN / 64;            // waves along N (4 or 2)
  constexpr int RM   = 256 / (8 / WN);     // rows per wave (128 or 64)
  constexpr int MI   = RM / 16;            // A-frags per wave (8 or 4)
  constexpr int NL   = (256 + BN) / 128;   // gloads per thread per K-tile (4 or 3)
  constexpr int BUFE = (256 + BN) * 32;    // elems per LDS buffer
  constexpr int NT   = DIMSZ / 32;         // 64 K-tiles

  __shared__ unsigned short lds[4 * BUFE];

  const unsigned short* Bm = (blockIdx.z == 0) ? B0 : ((blockIdx.z == 1) ? B1 : B2);
  const float* bias        = (blockIdx.z == 0) ? bias0 : ((blockIdx.z == 1) ? bias1 : bias2);
  float* C                 = (blockIdx.z == 0) ? C0 : ((blockIdx.z == 1) ? C1 : C2);

  const int tid = threadIdx.x;
  const int w = tid >> 6, l = tid & 63;
  const int lr = l & 15, lg = l >> 4;
  const int m0 = blockIdx.x * 256, n0 = blockIdx.y * BN;
  const int wr = (w / WN) * RM, wc = (w % WN) * 64;

  f32x4 acc[MI][4];
  #pragma unroll
  for (int mi = 0; mi < MI; ++mi)
    #pragma unroll
    for (int ni = 0; ni < 4; ++ni)
      acc[mi][ni] = (f32x4){0.f, 0.f, 0.f, 0.f};

#define G8_STAGE(TT) do{                                                          \
    const int k0s = (TT) * 32;                                                    \
    unsigned short* dst = &lds[((TT) & 3) * BUFE];                                \
    _Pragma("unroll")                                                             \
    for (int i_ = 0; i_ < 2; ++i_){                                               \
      int lin = i_ * 512 + tid;                                                   \
      int r_ = lin >> 2, pos_ = lin & 3;                                          \
      int gr_ = m0 + r_; if (gr_ > Mreal - 1) gr_ = Mreal - 1;                    \
      gload16(A + (size_t)gr_ * DIMSZ + k0s + (pos_ ^ ((r_ >> 1) & 3)) * 8,       \
              dst + lin * 8);                                                     \
    }                                                                             \
    _Pragma("unroll")                                                             \
    for (int i_ = 0; i_ < BN / 128; ++i_){                                        \
      int lin = i_ * 512 + tid;                                                   \
      int r_ = lin >> 2, pos_ = lin & 3;                                          \
      gload16(Bm + (size_t)(n0 + r_) * DIMSZ + k0s + (pos_ ^ ((r_ >> 1) & 3)) * 8,\
              dst + 8192 + lin * 8);                                              \
    }                                                                             \
  } while(0)

#define G8_COMPUTE(TT) do{                                                        \
    const unsigned short* sb = &lds[((TT) & 3) * BUFE];                           \
    bf16x8 af_[MI]; bf16x8 bf_[4];                                                \
    _Pragma("unroll")                                                             \
    for (int mi = 0; mi < MI; ++mi){                                              \
      int r_ = wr + mi * 16 + lr;                                                 \
      af_[mi] = *(const bf16x8*)(sb + r_ * 32 + (lg ^ ((r_ >> 1) & 3)) * 8);      \
    }                                                                             \
    _Pragma("unroll")                                                             \
    for (int ni = 0; ni < 4; ++ni){                                               \
      int r_ = wc + ni * 16 + lr;                                                 \
      bf_[ni] = *(const bf16x8*)(sb + 8192 + r_ * 32 + (lg ^ ((r_ >> 1) & 3)) * 8);\
    }                                                                             \
    __builtin_amdgcn_s_setprio(1);                                                \
    _Pragma("unroll")                                                             \
    for (int mi = 0; mi < MI; ++mi)                                               \
      _Pragma("unroll")                                                           \
      for (int ni = 0; ni < 4; ++ni)                                              \
        acc[mi][ni] = __builtin_amdgcn_mfma_f32_16x16x32_bf16(af_[mi], bf_[ni],   \
                                                              acc[mi][ni], 0, 0, 0);\
    __builtin_amdgcn_s_setprio(0);                                                \
  } while(0)

  // prologue: 3 K-tiles in flight
  G8_STAGE(0); G8_STAGE(1); G8_STAGE(2);

  for (int tt = 0; tt < NT - 3; ++tt){
    waitbar<2 * NL>();        // retire tile tt's loads; keep 2 tiles in flight
    G8_STAGE(tt + 3);
    G8_COMPUTE(tt);
  }
  waitbar<2 * NL>(); G8_COMPUTE(NT - 3);
  waitbar<NL>();     G8_COMPUTE(NT - 2);
  waitbar<0>();      G8_COMPUTE(NT - 1);

#undef G8_STAGE
#undef G8_COMPUTE

  #pragma unroll
  for (int ni = 0; ni < 4; ++ni){
    int col = n0 + wc + ni * 16 + lr;
    float bz = bias[col];
    #pragma unroll
    for (int mi = 0; mi < MI; ++mi){
      #pragma unroll
      for (int j = 0; j < 4; ++j){
        int row = m0 + wr + mi * 16 + lg * 4 + j;
        if (row < Mreal) C[(size_t)row * DIMSZ + col] = acc[mi][ni][j] + bz;
      }
    }
  }
}

// ---------------- RMSNorm + RoPE -> bf16 head layout [h][s_pad][128] ----------------
__launch_bounds__(256)
__global__ void k_normrope(const float* __restrict__ Xf, const float* __restrict__ nw,
                           const float* __restrict__ fc, const float* __restrict__ fs,
                           unsigned short* __restrict__ Out, float scale, int swz)
{
  const int s = blockIdx.x;
  const int t = threadIdx.x;
  const int w = t >> 6, l = t & 63;
  __shared__ float wred[4];
  float v[8];
  float ss = 0.f;
  if (s < S_REAL){
    const float4* p = (const float4*)(Xf + (size_t)s * DIMSZ) + t * 2;
    float4 a = p[0], b = p[1];
    v[0]=a.x; v[1]=a.y; v[2]=a.z; v[3]=a.w; v[4]=b.x; v[5]=b.y; v[6]=b.z; v[7]=b.w;
    #pragma unroll
    for (int j = 0; j < 8; ++j) ss += v[j] * v[j];
  }
  #pragma unroll
  for (int off = 32; off >= 1; off >>= 1) ss += __shfl_xor(ss, off);
  if (l == 0) wred[w] = ss;
  __syncthreads();
  float tot = wred[0] + wred[1] + wred[2] + wred[3];
  float rinv = rsqrtf(tot * (1.f / DIMSZ) + 1e-6f);

  const int h  = t >> 4;
  const int d0 = (t & 15) * 8;
  const int b  = t & 15;
  const int bsw = swz ? (b ^ (s & 7)) : b;
  unsigned short* dst = Out + ((size_t)h * S_PAD + s) * DHD + bsw * 8;
  u16x8 o;
  if (s < S_REAL){
    #pragma unroll
    for (int i = 0; i < 4; ++i){
      float c_ = fc[s * DHD + d0 + 2 * i];
      float s_ = fs[s * DHD + d0 + 2 * i + 1];
      float x1 = v[2 * i]     * rinv * nw[t * 8 + 2 * i];
      float x2 = v[2 * i + 1] * rinv * nw[t * 8 + 2 * i + 1];
      o[2 * i]     = f2bf((x1 * c_ - x2 * s_) * scale);
      o[2 * i + 1] = f2bf((x1 * s_ + x2 * c_) * scale);
    }
  } else {
    #pragma unroll
    for (int j = 0; j < 8; ++j) o[j] = 0;
  }
  *(u16x8*)dst = o;
}

// ---------------- V transpose: fp32 [s][2048] -> bf16 [c=h*128+d][s_pad], swizzled ----
__launch_bounds__(256)
__global__ void k_vtrans(const float* __restrict__ Vf, unsigned short* __restrict__ Vth)
{
  __shared__ unsigned short tile[64][72];
  const int t = threadIdx.x;
  const int s0 = blockIdx.x * 64, c0 = blockIdx.y * 64;
  #pragma unroll
  for (int i = 0; i < 4; ++i){
    int r = (t >> 4) * 4 + i;
    int s = s0 + r;
    int cq = (t & 15) * 4;
    float4 val = {0.f, 0.f, 0.f, 0.f};
    if (s < S_REAL) val = *((const float4*)(Vf + (size_t)s * DIMSZ + c0) + (t & 15));
    tile[r][cq + 0] = f2bf(val.x);
    tile[r][cq + 1] = f2bf(val.y);
    tile[r][cq + 2] = f2bf(val.z);
    tile[r][cq + 3] = f2bf(val.w);
  }
  __syncthreads();
  const int cl = t >> 2;
  const int cc = c0 + cl;
  #pragma unroll
  for (int bi = 0; bi < 2; ++bi){
    int b = (t & 3) * 2 + bi;
    u16x8 o;
    #pragma unroll
    for (int j = 0; j < 8; ++j) o[j] = tile[b * 8 + j][cl];
    int bsw = b ^ (cc & 7);
    *(u16x8*)(Vth + (size_t)cc * S_PAD + s0 + bsw * 8) = o;
  }
}

// ---------------- flash attention: 4 waves x 16 q-rows, KV tiles of 64 ----------------
__launch_bounds__(256)
__global__ void k_attn(const unsigned short* __restrict__ Qh,
                       const unsigned short* __restrict__ Kh,
                       const unsigned short* __restrict__ Vth,
                       unsigned short* __restrict__ O)
{
  __shared__ unsigned short kbuf[64 * 128];
  __shared__ unsigned short vbuf[128 * 64];
  __shared__ unsigned short pbuf[4][16 * 64];
  const int h = blockIdx.y;
  const int q0 = blockIdx.x * 64;
  const int t = threadIdx.x, w = t >> 6, l = t & 63;
  const int lr = l & 15, lg = l >> 4;

  const unsigned short* Qp = Qh + ((size_t)h * S_PAD + q0 + w * 16 + lr) * DHD;
  bf16x8 qf[4];
  #pragma unroll
  for (int ks = 0; ks < 4; ++ks) qf[ks] = *(const bf16x8*)(Qp + ks * 32 + lg * 8);

  f32x4 acc[8];
  #pragma unroll
  for (int nf = 0; nf < 8; ++nf) acc[nf] = (f32x4){0.f, 0.f, 0.f, 0.f};
  float m[4], lsum[4];
  #pragma unroll
  for (int j = 0; j < 4; ++j){ m[j] = -3.0e38f; lsum[j] = 0.f; }

  for (int kt = 0; kt < S_PAD / 64; ++kt){
    __syncthreads();
    #pragma unroll
    for (int i = 0; i < 4; ++i){
      int rK = (w * 4 + i) * 4 + (l >> 4);
      gload16(Kh + ((size_t)h * S_PAD + kt * 64 + rK) * DHD + (l & 15) * 8, &kbuf[(w * 4 + i) * 512]);
      int rV = (w * 4 + i) * 8 + (l >> 3);
      gload16(Vth + ((size_t)h * DHD + rV) * S_PAD + kt * 64 + (l & 7) * 8, &vbuf[(w * 4 + i) * 512]);
    }
    __syncthreads();

    f32x4 sf[4];
    #pragma unroll
    for (int kvf = 0; kvf < 4; ++kvf){
      sf[kvf] = (f32x4){0.f, 0.f, 0.f, 0.f};
      int r = kvf * 16 + lr;
      #pragma unroll
      for (int ks = 0; ks < 4; ++ks){
        int blk = (ks * 4 + lg) ^ (r & 7);
        bf16x8 kf = *(const bf16x8*)&kbuf[r * 128 + blk * 8];
        sf[kvf] = __builtin_amdgcn_mfma_f32_16x16x32_bf16(qf[ks], kf, sf[kvf], 0, 0, 0);
      }
    }

    float rowmax[4], rowsum[4], fr[4];
    #pragma unroll
    for (int j = 0; j < 4; ++j)
      rowmax[j] = fmaxf(fmaxf(sf[0][j], sf[1][j]), fmaxf(sf[2][j], sf[3][j]));
    #pragma unroll
    for (int off = 1; off <= 8; off <<= 1)
      #pragma unroll
      for (int j = 0; j < 4; ++j) rowmax[j] = fmaxf(rowmax[j], __shfl_xor(rowmax[j], off));
    #pragma unroll
    for (int j = 0; j < 4; ++j){
      float mn = fmaxf(m[j], rowmax[j]);
      fr[j] = __expf(m[j] - mn);
      m[j] = mn;
    }
    float p[4][4];
    #pragma unroll
    for (int kvf = 0; kvf < 4; ++kvf)
      #pragma unroll
      for (int j = 0; j < 4; ++j) p[kvf][j] = __expf(sf[kvf][j] - m[j]);
    #pragma unroll
    for (int j = 0; j < 4; ++j) rowsum[j] = p[0][j] + p[1][j] + p[2][j] + p[3][j];
    #pragma unroll
    for (int off = 1; off <= 8; off <<= 1)
      #pragma unroll
      for (int j = 0; j < 4; ++j) rowsum[j] += __shfl_xor(rowsum[j], off);
    f32x4 fv = (f32x4){fr[0], fr[1], fr[2], fr[3]};
    #pragma unroll
    for (int j = 0; j < 4; ++j) lsum[j] = lsum[j] * fr[j] + rowsum[j];
    #pragma unroll
    for (int nf = 0; nf < 8; ++nf) acc[nf] *= fv;

    unsigned short* pb = pbuf[w];
    #pragma unroll
    for (int kvf = 0; kvf < 4; ++kvf)
      #pragma unroll
      for (int j = 0; j < 4; ++j){
        int r = lg * 4 + j;
        int c = kvf * 16 + lr;
        int blk = (c >> 3) ^ (r & 7);
        pb[r * 64 + blk * 8 + (c & 7)] = f2bf(p[kvf][j]);
      }

    bf16x8 pf[2];
    #pragma unroll
    for (int ks = 0; ks < 2; ++ks){
      int blk = (ks * 4 + lg) ^ (lr & 7);
      pf[ks] = *(const bf16x8*)&pb[lr * 64 + blk * 8];
    }
    #pragma unroll
    for (int nf = 0; nf < 8; ++nf){
      int c = nf * 16 + lr;
      #pragma unroll
      for (int ks = 0; ks < 2; ++ks){
        int blk = (ks * 4 + lg) ^ (c & 7);
        bf16x8 vf = *(const bf16x8*)&vbuf[c * 64 + blk * 8];
        acc[nf] = __builtin_amdgcn_mfma_f32_16x16x32_bf16(pf[ks], vf, acc[nf], 0, 0, 0);
      }
    }
  }

  #pragma unroll
  for (int nf = 0; nf < 8; ++nf){
    #pragma unroll
    for (int j = 0; j < 4; ++j){
      int row = q0 + w * 16 + lg * 4 + j;
      if (row < S_REAL)
        O[(size_t)row * DIMSZ + h * DHD + nf * 16 + lr] = f2bf(acc[nf][j] / lsum[j]);
    }
  }
}

extern "C" void kernel_launch(void* const* d_in, const int* in_sizes, int n_in,
                              void* d_out, int out_size, void* d_ws, size_t ws_size,
                              hipStream_t stream)
{
  const float* hidden = (const float*)d_in[0];
  const float* fc  = (const float*)d_in[1];
  const float* fs  = (const float*)d_in[2];
  const float* wq  = (const float*)d_in[3];
  const float* bq  = (const float*)d_in[4];
  const float* wk  = (const float*)d_in[5];
  const float* bk  = (const float*)d_in[6];
  const float* wv  = (const float*)d_in[7];
  const float* bv  = (const float*)d_in[8];
  const float* nqw = (const float*)d_in[9];
  const float* nkw = (const float*)d_in[10];
  const float* wo  = (const float*)d_in[11];
  const float* bo  = (const float*)d_in[12];
  float* out = (float*)d_out;

  char* ws = (char*)d_ws;
  size_t off = 0;
  auto alloc = [&](size_t bytes) -> void* {
    void* p = ws + off;
    off += (bytes + 255) & ~(size_t)255;
    return p;
  };
  unsigned short* Xb  = (unsigned short*)alloc((size_t)S_REAL * DIMSZ * 2);
  unsigned short* Wqb = (unsigned short*)alloc((size_t)DIMSZ * DIMSZ * 2);
  unsigned short* Wkb = (unsigned short*)alloc((size_t)DIMSZ * DIMSZ * 2);
  unsigned short* Wvb = (unsigned short*)alloc((size_t)DIMSZ * DIMSZ * 2);
  unsigned short* Wob = (unsigned short*)alloc((size_t)DIMSZ * DIMSZ * 2);
  float* Qf = (float*)alloc((size_t)S_REAL * DIMSZ * 4);
  float* Kf = (float*)alloc((size_t)S_REAL * DIMSZ * 4);
  float* Vf = (float*)alloc((size_t)S_REAL * DIMSZ * 4);
  unsigned short* Qhh = (unsigned short*)alloc((size_t)NHEAD * S_PAD * DHD * 2);
  unsigned short* Khh = (unsigned short*)alloc((size_t)NHEAD * S_PAD * DHD * 2);
  unsigned short* Vth = (unsigned short*)alloc((size_t)NHEAD * DHD * S_PAD * 2);
  unsigned short* Oa  = (unsigned short*)alloc((size_t)S_REAL * DIMSZ * 2);

  k_cvt<<<S_REAL * DIMSZ / 8 / 256, 256, 0, stream>>>(hidden, Xb, S_REAL * DIMSZ / 8);
  k_cvt<<<DIMSZ * DIMSZ / 8 / 256, 256, 0, stream>>>(wq, Wqb, DIMSZ * DIMSZ / 8);
  k_cvt<<<DIMSZ * DIMSZ / 8 / 256, 256, 0, stream>>>(wk, Wkb, DIMSZ * DIMSZ / 8);
  k_cvt<<<DIMSZ * DIMSZ / 8 / 256, 256, 0, stream>>>(wv, Wvb, DIMSZ * DIMSZ / 8);
  k_cvt<<<DIMSZ * DIMSZ / 8 / 256, 256, 0, stream>>>(wo, Wob, DIMSZ * DIMSZ / 8);

  // fused QKV projection: 256x256 tiles, 8x8x3 = 192 blocks
  k_gemm8<256><<<dim3(8, 8, 3), 512, 0, stream>>>(Xb, Wqb, Wkb, Wvb, bq, bk, bv,
                                                  Qf, Kf, Vf, S_REAL);

  k_normrope<<<S_PAD, 256, 0, stream>>>(Qf, nqw, fc, fs, Qhh, 0.08838834764831843f, 0);
  k_normrope<<<S_PAD, 256, 0, stream>>>(Kf, nkw, fc, fs, Khh, 1.0f, 1);

  k_vtrans<<<dim3(S_PAD / 64, DIMSZ / 64), 256, 0, stream>>>(Vf, Vth);

  k_attn<<<dim3(S_PAD / 64, NHEAD), 256, 0, stream>>>(Qhh, Khh, Vth, Oa);

  // output projection: 256x128 tiles, 8x16 = 128 blocks
  k_gemm8<128><<<dim3(8, 16, 1), 512, 0, stream>>>(Oa, Wob, Wob, Wob, bo, bo, bo,
                                                   out, out, out, S_REAL);
}

// Round 3
// 218.597 us; speedup vs baseline: 1.3984x; 1.1713x over previous
//
#include <hip/hip_runtime.h>
#include <cstdint>

#define S_REAL 1992
#define S_PAD  2048
#define DIMSZ  2048
#define NHEAD  16
#define DHD    128

typedef float f32x4 __attribute__((ext_vector_type(4)));
typedef __bf16 bf16x8 __attribute__((ext_vector_type(8)));
typedef unsigned short u16x8 __attribute__((ext_vector_type(8)));

__device__ __forceinline__ unsigned short f2bf(float f){
  uint32_t u = __float_as_uint(f);
  u += 0x7fffu + ((u >> 16) & 1u);
  return (unsigned short)(u >> 16);
}

__device__ __forceinline__ void gload16(const void* g, void* l){
  __builtin_amdgcn_global_load_lds(
      (const __attribute__((address_space(1))) uint32_t*)g,
      (__attribute__((address_space(3))) uint32_t*)l,
      16, 0, 0);
}

template<int N> __device__ __forceinline__ void waitbar(){
  if constexpr (N == 8)      asm volatile("s_waitcnt vmcnt(8)\n\ts_barrier" ::: "memory");
  else if constexpr (N == 6) asm volatile("s_waitcnt vmcnt(6)\n\ts_barrier" ::: "memory");
  else if constexpr (N == 4) asm volatile("s_waitcnt vmcnt(4)\n\ts_barrier" ::: "memory");
  else if constexpr (N == 3) asm volatile("s_waitcnt vmcnt(3)\n\ts_barrier" ::: "memory");
  else if constexpr (N == 2) asm volatile("s_waitcnt vmcnt(2)\n\ts_barrier" ::: "memory");
  else                       asm volatile("s_waitcnt vmcnt(0)\n\ts_barrier" ::: "memory");
}

// ---------------- fp32 -> bf16 convert (vectorized) ----------------
__launch_bounds__(256)
__global__ void k_cvt(const float* __restrict__ src, unsigned short* __restrict__ dst, int n8){
  int i = blockIdx.x * 256 + threadIdx.x;
  if (i >= n8) return;
  const float4* s = (const float4*)src + (size_t)i * 2;
  float4 a = s[0], b = s[1];
  u16x8 o;
  o[0]=f2bf(a.x); o[1]=f2bf(a.y); o[2]=f2bf(a.z); o[3]=f2bf(a.w);
  o[4]=f2bf(b.x); o[5]=f2bf(b.y); o[6]=f2bf(b.z); o[7]=f2bf(b.w);
  *((u16x8*)dst + i) = o;
}

// ---------------- deep-pipelined GEMM: C[m][n] = sum_k A[m][k]*W[n][k] + bias[n] ----
// BM x BN tile, 8 waves (512 thr), BK=32, 4 LDS buffers, loads 3 tiles in flight.
template<int BM, int BN>
__launch_bounds__(512, 2)
__global__ void k_gemm8(const unsigned short* __restrict__ A,
                        const unsigned short* __restrict__ B0,
                        const unsigned short* __restrict__ B1,
                        const unsigned short* __restrict__ B2,
                        const float* __restrict__ bias0,
                        const float* __restrict__ bias1,
                        const float* __restrict__ bias2,
                        float* __restrict__ C0, float* __restrict__ C1, float* __restrict__ C2,
                        int Mreal)
{
  constexpr int WN   = BN / 64;            // waves along N
  constexpr int WM   = 8 / WN;             // waves along M
  constexpr int RM   = BM / WM;            // rows per wave
  constexpr int MI   = RM / 16;            // A-frags per wave
  constexpr int NL   = (BM + BN) / 128;    // gloads per thread per K-tile
  constexpr int BUFE = (BM + BN) * 32;     // elems per LDS buffer
  constexpr int BOFF = BM * 32;            // B-tile offset within buffer
  constexpr int NT   = DIMSZ / 32;         // 64 K-tiles

  __shared__ unsigned short lds[4 * BUFE];

  const unsigned short* Bm = (blockIdx.z == 0) ? B0 : ((blockIdx.z == 1) ? B1 : B2);
  const float* bias        = (blockIdx.z == 0) ? bias0 : ((blockIdx.z == 1) ? bias1 : bias2);
  float* C                 = (blockIdx.z == 0) ? C0 : ((blockIdx.z == 1) ? C1 : C2);

  const int tid = threadIdx.x;
  const int w = tid >> 6, l = tid & 63;
  const int lr = l & 15, lg = l >> 4;
  const int m0 = blockIdx.x * BM, n0 = blockIdx.y * BN;
  const int wr = (w / WN) * RM, wc = (w % WN) * 64;

  f32x4 acc[MI][4];
  #pragma unroll
  for (int mi = 0; mi < MI; ++mi)
    #pragma unroll
    for (int ni = 0; ni < 4; ++ni)
      acc[mi][ni] = (f32x4){0.f, 0.f, 0.f, 0.f};

#define G8_STAGE(TT) do{                                                          \
    const int k0s = (TT) * 32;                                                    \
    unsigned short* dst = &lds[((TT) & 3) * BUFE];                                \
    _Pragma("unroll")                                                             \
    for (int i_ = 0; i_ < BM / 128; ++i_){                                        \
      int lin = i_ * 512 + tid;                                                   \
      int r_ = lin >> 2, pos_ = lin & 3;                                          \
      int gr_ = m0 + r_; if (gr_ > Mreal - 1) gr_ = Mreal - 1;                    \
      gload16(A + (size_t)gr_ * DIMSZ + k0s + (pos_ ^ ((r_ >> 1) & 3)) * 8,       \
              dst + lin * 8);                                                     \
    }                                                                             \
    _Pragma("unroll")                                                             \
    for (int i_ = 0; i_ < BN / 128; ++i_){                                        \
      int lin = i_ * 512 + tid;                                                   \
      int r_ = lin >> 2, pos_ = lin & 3;                                          \
      gload16(Bm + (size_t)(n0 + r_) * DIMSZ + k0s + (pos_ ^ ((r_ >> 1) & 3)) * 8,\
              dst + BOFF + lin * 8);                                              \
    }                                                                             \
  } while(0)

#define G8_COMPUTE(TT) do{                                                        \
    const unsigned short* sb = &lds[((TT) & 3) * BUFE];                           \
    bf16x8 af_[MI]; bf16x8 bf_[4];                                                \
    _Pragma("unroll")                                                             \
    for (int mi = 0; mi < MI; ++mi){                                              \
      int r_ = wr + mi * 16 + lr;                                                 \
      af_[mi] = *(const bf16x8*)(sb + r_ * 32 + (lg ^ ((r_ >> 1) & 3)) * 8);      \
    }                                                                             \
    _Pragma("unroll")                                                             \
    for (int ni = 0; ni < 4; ++ni){                                               \
      int r_ = wc + ni * 16 + lr;                                                 \
      bf_[ni] = *(const bf16x8*)(sb + BOFF + r_ * 32 + (lg ^ ((r_ >> 1) & 3)) * 8);\
    }                                                                             \
    __builtin_amdgcn_s_setprio(1);                                                \
    _Pragma("unroll")                                                             \
    for (int mi = 0; mi < MI; ++mi)                                               \
      _Pragma("unroll")                                                           \
      for (int ni = 0; ni < 4; ++ni)                                              \
        acc[mi][ni] = __builtin_amdgcn_mfma_f32_16x16x32_bf16(af_[mi], bf_[ni],   \
                                                              acc[mi][ni], 0, 0, 0);\
    __builtin_amdgcn_s_setprio(0);                                                \
  } while(0)

  G8_STAGE(0); G8_STAGE(1); G8_STAGE(2);

  for (int tt = 0; tt < NT - 3; ++tt){
    waitbar<2 * NL>();
    G8_STAGE(tt + 3);
    G8_COMPUTE(tt);
  }
  waitbar<2 * NL>(); G8_COMPUTE(NT - 3);
  waitbar<NL>();     G8_COMPUTE(NT - 2);
  waitbar<0>();      G8_COMPUTE(NT - 1);

#undef G8_STAGE
#undef G8_COMPUTE

  #pragma unroll
  for (int ni = 0; ni < 4; ++ni){
    int col = n0 + wc + ni * 16 + lr;
    float bz = bias[col];
    #pragma unroll
    for (int mi = 0; mi < MI; ++mi){
      #pragma unroll
      for (int j = 0; j < 4; ++j){
        int row = m0 + wr + mi * 16 + lg * 4 + j;
        if (row < Mreal) C[(size_t)row * DIMSZ + col] = acc[mi][ni][j] + bz;
      }
    }
  }
}

// ---------------- RMSNorm + RoPE -> bf16 head layout [h][s_pad][128] ----------------
__launch_bounds__(256)
__global__ void k_normrope(const float* __restrict__ Xf, const float* __restrict__ nw,
                           const float* __restrict__ fc, const float* __restrict__ fs,
                           unsigned short* __restrict__ Out, float scale, int swz)
{
  const int s = blockIdx.x;
  const int t = threadIdx.x;
  const int w = t >> 6, l = t & 63;
  __shared__ float wred[4];
  float v[8];
  float ss = 0.f;
  if (s < S_REAL){
    const float4* p = (const float4*)(Xf + (size_t)s * DIMSZ) + t * 2;
    float4 a = p[0], b = p[1];
    v[0]=a.x; v[1]=a.y; v[2]=a.z; v[3]=a.w; v[4]=b.x; v[5]=b.y; v[6]=b.z; v[7]=b.w;
    #pragma unroll
    for (int j = 0; j < 8; ++j) ss += v[j] * v[j];
  }
  #pragma unroll
  for (int off = 32; off >= 1; off >>= 1) ss += __shfl_xor(ss, off);
  if (l == 0) wred[w] = ss;
  __syncthreads();
  float tot = wred[0] + wred[1] + wred[2] + wred[3];
  float rinv = rsqrtf(tot * (1.f / DIMSZ) + 1e-6f);

  const int h  = t >> 4;
  const int d0 = (t & 15) * 8;
  const int b  = t & 15;
  const int bsw = swz ? (b ^ (s & 7)) : b;
  unsigned short* dst = Out + ((size_t)h * S_PAD + s) * DHD + bsw * 8;
  u16x8 o;
  if (s < S_REAL){
    #pragma unroll
    for (int i = 0; i < 4; ++i){
      float c_ = fc[s * DHD + d0 + 2 * i];
      float s_ = fs[s * DHD + d0 + 2 * i + 1];
      float x1 = v[2 * i]     * rinv * nw[t * 8 + 2 * i];
      float x2 = v[2 * i + 1] * rinv * nw[t * 8 + 2 * i + 1];
      o[2 * i]     = f2bf((x1 * c_ - x2 * s_) * scale);
      o[2 * i + 1] = f2bf((x1 * s_ + x2 * c_) * scale);
    }
  } else {
    #pragma unroll
    for (int j = 0; j < 8; ++j) o[j] = 0;
  }
  *(u16x8*)dst = o;
}

// ---------------- V transpose: fp32 [s][2048] -> bf16 [c=h*128+d][s_pad], swizzled ----
__launch_bounds__(256)
__global__ void k_vtrans(const float* __restrict__ Vf, unsigned short* __restrict__ Vth)
{
  __shared__ unsigned short tile[64][72];
  const int t = threadIdx.x;
  const int s0 = blockIdx.x * 64, c0 = blockIdx.y * 64;
  #pragma unroll
  for (int i = 0; i < 4; ++i){
    int r = (t >> 4) * 4 + i;
    int s = s0 + r;
    int cq = (t & 15) * 4;
    float4 val = {0.f, 0.f, 0.f, 0.f};
    if (s < S_REAL) val = *((const float4*)(Vf + (size_t)s * DIMSZ + c0) + (t & 15));
    tile[r][cq + 0] = f2bf(val.x);
    tile[r][cq + 1] = f2bf(val.y);
    tile[r][cq + 2] = f2bf(val.z);
    tile[r][cq + 3] = f2bf(val.w);
  }
  __syncthreads();
  const int cl = t >> 2;
  const int cc = c0 + cl;
  #pragma unroll
  for (int bi = 0; bi < 2; ++bi){
    int b = (t & 3) * 2 + bi;
    u16x8 o;
    #pragma unroll
    for (int j = 0; j < 8; ++j) o[j] = tile[b * 8 + j][cl];
    int bsw = b ^ (cc & 7);
    *(u16x8*)(Vth + (size_t)cc * S_PAD + s0 + bsw * 8) = o;
  }
}

// ---------------- flash attention: swapped-QK^T, 2-phase pipelined ----------------
// 4 waves x 16 q-rows, KV tiles of 64, double-buffered K/V.
// Swapped S = mfma(K,Q): lane holds P[kv=16kvf+4lg+j][q=lr] -> row softmax is
// 15 local max + 2 shfl_xor; row-sum deferred to end (per-lane partials).
__launch_bounds__(256)
__global__ void k_attn(const unsigned short* __restrict__ Qh,
                       const unsigned short* __restrict__ Kh,
                       const unsigned short* __restrict__ Vth,
                       unsigned short* __restrict__ O)
{
  __shared__ unsigned short kbuf[2][64 * 128];   // 16KB each
  __shared__ unsigned short vbuf[2][128 * 64];   // 16KB each
  __shared__ unsigned short pbuf[4][16 * 64];    // per-wave P [q][kv], swizzled
  const int h = blockIdx.y;
  const int q0 = blockIdx.x * 64;
  const int t = threadIdx.x, w = t >> 6, l = t & 63;
  const int lr = l & 15, lg = l >> 4;

  // Q fragment (B-operand of swapped QK^T; also A-layout identical)
  const unsigned short* Qp = Qh + ((size_t)h * S_PAD + q0 + w * 16 + lr) * DHD;
  bf16x8 qf[4];
  #pragma unroll
  for (int ks = 0; ks < 4; ++ks) qf[ks] = *(const bf16x8*)(Qp + ks * 32 + lg * 8);

  f32x4 acc[8];
  #pragma unroll
  for (int nf = 0; nf < 8; ++nf) acc[nf] = (f32x4){0.f, 0.f, 0.f, 0.f};
  float m = -3.0e38f, lsum = 0.f;

#define ATT_STAGE(KT, BI) do{                                                       \
    _Pragma("unroll")                                                               \
    for (int i_ = 0; i_ < 4; ++i_){                                                 \
      int rK = (w * 4 + i_) * 4 + (l >> 4);                                         \
      gload16(Kh + ((size_t)h * S_PAD + (KT) * 64 + rK) * DHD + (l & 15) * 8,       \
              &kbuf[BI][(w * 4 + i_) * 512]);                                       \
      int rV = (w * 4 + i_) * 8 + (l >> 3);                                         \
      gload16(Vth + ((size_t)h * DHD + rV) * S_PAD + (KT) * 64 + (l & 7) * 8,       \
              &vbuf[BI][(w * 4 + i_) * 512]);                                       \
    }                                                                               \
  } while(0)

  ATT_STAGE(0, 0);
  __syncthreads();

  for (int kt = 0; kt < S_PAD / 64; ++kt){
    const int bi = kt & 1;
    if (kt < S_PAD / 64 - 1) ATT_STAGE(kt + 1, bi ^ 1);

    // S^T = K Q^T : lane holds P[kv=16kvf+4lg+j][q=lr]
    f32x4 sf[4];
    __builtin_amdgcn_s_setprio(1);
    #pragma unroll
    for (int kvf = 0; kvf < 4; ++kvf){
      sf[kvf] = (f32x4){0.f, 0.f, 0.f, 0.f};
      int r = kvf * 16 + lr;
      #pragma unroll
      for (int ks = 0; ks < 4; ++ks){
        int blk = (ks * 4 + lg) ^ (r & 7);
        bf16x8 kf = *(const bf16x8*)&kbuf[bi][r * 128 + blk * 8];
        sf[kvf] = __builtin_amdgcn_mfma_f32_16x16x32_bf16(kf, qf[ks], sf[kvf], 0, 0, 0);
      }
    }
    __builtin_amdgcn_s_setprio(0);

    // online softmax for row q=lr (row spread over lanes {l, l^16, l^32, l^48})
    float pmax = sf[0][0];
    #pragma unroll
    for (int kvf = 0; kvf < 4; ++kvf)
      #pragma unroll
      for (int j = 0; j < 4; ++j) pmax = fmaxf(pmax, sf[kvf][j]);
    pmax = fmaxf(pmax, __shfl_xor(pmax, 16));
    pmax = fmaxf(pmax, __shfl_xor(pmax, 32));
    float mn = fmaxf(m, pmax);
    float fr = __expf(m - mn);
    m = mn;
    float p[4][4];
    float psum = 0.f;
    #pragma unroll
    for (int kvf = 0; kvf < 4; ++kvf)
      #pragma unroll
      for (int j = 0; j < 4; ++j){ p[kvf][j] = __expf(sf[kvf][j] - mn); psum += p[kvf][j]; }
    lsum = lsum * fr + psum;

    // rescale acc rows (acc row j corresponds to q = lg*4+j)
    float fv0 = __shfl(fr, lg * 4 + 0);
    float fv1 = __shfl(fr, lg * 4 + 1);
    float fv2 = __shfl(fr, lg * 4 + 2);
    float fv3 = __shfl(fr, lg * 4 + 3);
    f32x4 fv = (f32x4){fv0, fv1, fv2, fv3};
    #pragma unroll
    for (int nf = 0; nf < 8; ++nf) acc[nf] *= fv;

    // stage P[q=lr][kv] as packed bf16 pairs: 4x ds_write_b64, swizzled 16B blocks
    char* pb = (char*)pbuf[w];
    #pragma unroll
    for (int kvf = 0; kvf < 4; ++kvf){
      uint2 wv;
      wv.x = (uint32_t)f2bf(p[kvf][0]) | ((uint32_t)f2bf(p[kvf][1]) << 16);
      wv.y = (uint32_t)f2bf(p[kvf][2]) | ((uint32_t)f2bf(p[kvf][3]) << 16);
      int byte = lr * 128 + (((kvf * 2 + (lg >> 1)) ^ (lr & 7)) * 16) + (lg & 1) * 8;
      *(uint2*)(pb + byte) = wv;
    }
    // read A-frag P[q=lr][kv = c*32 + lg*8 ..]
    bf16x8 pf[2];
    #pragma unroll
    for (int c = 0; c < 2; ++c)
      pf[c] = *(const bf16x8*)(pb + lr * 128 + ((c * 4 + lg) ^ (lr & 7)) * 16);

    // O += P V
    __builtin_amdgcn_s_setprio(1);
    #pragma unroll
    for (int nf = 0; nf < 8; ++nf){
      int cc = nf * 16 + lr;
      #pragma unroll
      for (int ks = 0; ks < 2; ++ks){
        int blk = (ks * 4 + lg) ^ (cc & 7);
        bf16x8 vf = *(const bf16x8*)&vbuf[bi][cc * 64 + blk * 8];
        acc[nf] = __builtin_amdgcn_mfma_f32_16x16x32_bf16(pf[ks], vf, acc[nf], 0, 0, 0);
      }
    }
    __builtin_amdgcn_s_setprio(0);

    __syncthreads();
  }
#undef ATT_STAGE

  // finalize row sums (quad reduce), broadcast to acc row layout
  lsum += __shfl_xor(lsum, 16);
  lsum += __shfl_xor(lsum, 32);
  float ls0 = __shfl(lsum, lg * 4 + 0);
  float ls1 = __shfl(lsum, lg * 4 + 1);
  float ls2 = __shfl(lsum, lg * 4 + 2);
  float ls3 = __shfl(lsum, lg * 4 + 3);
  f32x4 lsv = (f32x4){1.f / ls0, 1.f / ls1, 1.f / ls2, 1.f / ls3};

  #pragma unroll
  for (int nf = 0; nf < 8; ++nf){
    #pragma unroll
    for (int j = 0; j < 4; ++j){
      int row = q0 + w * 16 + lg * 4 + j;
      if (row < S_REAL)
        O[(size_t)row * DIMSZ + h * DHD + nf * 16 + lr] = f2bf(acc[nf][j] * lsv[j]);
    }
  }
}

extern "C" void kernel_launch(void* const* d_in, const int* in_sizes, int n_in,
                              void* d_out, int out_size, void* d_ws, size_t ws_size,
                              hipStream_t stream)
{
  const float* hidden = (const float*)d_in[0];
  const float* fc  = (const float*)d_in[1];
  const float* fs  = (const float*)d_in[2];
  const float* wq  = (const float*)d_in[3];
  const float* bq  = (const float*)d_in[4];
  const float* wk  = (const float*)d_in[5];
  const float* bk  = (const float*)d_in[6];
  const float* wv  = (const float*)d_in[7];
  const float* bv  = (const float*)d_in[8];
  const float* nqw = (const float*)d_in[9];
  const float* nkw = (const float*)d_in[10];
  const float* wo  = (const float*)d_in[11];
  const float* bo  = (const float*)d_in[12];
  float* out = (float*)d_out;

  char* ws = (char*)d_ws;
  size_t off = 0;
  auto alloc = [&](size_t bytes) -> void* {
    void* p = ws + off;
    off += (bytes + 255) & ~(size_t)255;
    return p;
  };
  unsigned short* Xb  = (unsigned short*)alloc((size_t)S_REAL * DIMSZ * 2);
  unsigned short* Wqb = (unsigned short*)alloc((size_t)DIMSZ * DIMSZ * 2);
  unsigned short* Wkb = (unsigned short*)alloc((size_t)DIMSZ * DIMSZ * 2);
  unsigned short* Wvb = (unsigned short*)alloc((size_t)DIMSZ * DIMSZ * 2);
  unsigned short* Wob = (unsigned short*)alloc((size_t)DIMSZ * DIMSZ * 2);
  float* Qf = (float*)alloc((size_t)S_REAL * DIMSZ * 4);
  float* Kf = (float*)alloc((size_t)S_REAL * DIMSZ * 4);
  float* Vf = (float*)alloc((size_t)S_REAL * DIMSZ * 4);
  unsigned short* Qhh = (unsigned short*)alloc((size_t)NHEAD * S_PAD * DHD * 2);
  unsigned short* Khh = (unsigned short*)alloc((size_t)NHEAD * S_PAD * DHD * 2);
  unsigned short* Vth = (unsigned short*)alloc((size_t)NHEAD * DHD * S_PAD * 2);
  unsigned short* Oa  = (unsigned short*)alloc((size_t)S_REAL * DIMSZ * 2);

  k_cvt<<<S_REAL * DIMSZ / 8 / 256, 256, 0, stream>>>(hidden, Xb, S_REAL * DIMSZ / 8);
  k_cvt<<<DIMSZ * DIMSZ / 8 / 256, 256, 0, stream>>>(wq, Wqb, DIMSZ * DIMSZ / 8);
  k_cvt<<<DIMSZ * DIMSZ / 8 / 256, 256, 0, stream>>>(wk, Wkb, DIMSZ * DIMSZ / 8);
  k_cvt<<<DIMSZ * DIMSZ / 8 / 256, 256, 0, stream>>>(wv, Wvb, DIMSZ * DIMSZ / 8);
  k_cvt<<<DIMSZ * DIMSZ / 8 / 256, 256, 0, stream>>>(wo, Wob, DIMSZ * DIMSZ / 8);

  // fused QKV projection: 256x256 tiles
  k_gemm8<256, 256><<<dim3(8, 8, 3), 512, 0, stream>>>(Xb, Wqb, Wkb, Wvb, bq, bk, bv,
                                                       Qf, Kf, Vf, S_REAL);

  k_normrope<<<S_PAD, 256, 0, stream>>>(Qf, nqw, fc, fs, Qhh, 0.08838834764831843f, 0);
  k_normrope<<<S_PAD, 256, 0, stream>>>(Kf, nkw, fc, fs, Khh, 1.0f, 1);

  k_vtrans<<<dim3(S_PAD / 64, DIMSZ / 64), 256, 0, stream>>>(Vf, Vth);

  k_attn<<<dim3(S_PAD / 64, NHEAD), 256, 0, stream>>>(Qhh, Khh, Vth, Oa);

  // output projection: 128x128 tiles -> 256 blocks (full CU utilization)
  k_gemm8<128, 128><<<dim3(16, 16, 1), 512, 0, stream>>>(Oa, Wob, Wob, Wob, bo, bo, bo,
                                                         out, out, out, S_REAL);
}